// Round 8
// baseline (149.790 us; speedup 1.0000x reference)
//
#include <hip/hip_runtime.h>

#define IN_C 128
#define OUT_C 256
#define LN_EPS 1e-5f
#define SCAN_BLK 1024

typedef __attribute__((ext_vector_type(8))) short bf16x8;
typedef __attribute__((ext_vector_type(4))) float f32x4;

__device__ __forceinline__ unsigned int f2bf(float f) {
    unsigned int u = __float_as_uint(f);
    return (u + 0x7fffu + ((u >> 16) & 1u)) >> 16;   // RNE
}
__device__ __forceinline__ float bf_lo(unsigned int p) { return __uint_as_float(p << 16); }
__device__ __forceinline__ float bf_hi(unsigned int p) { return __uint_as_float(p & 0xffff0000u); }

// ---------- zero cursor ----------
__global__ __launch_bounds__(256) void k_zero(int4* __restrict__ p, int n4) {
    int i = blockIdx.x * 256 + threadIdx.x;
    if (i < n4) p[i] = (int4){0, 0, 0, 0};
}

// ---------- fused: slot reservation (atomics) + x->bf16 convert + weight fragments ----------
// Streaming convert traffic hides under device-scope atomic latency.
__global__ __launch_bounds__(256) void k_slotcvt(const int* __restrict__ col,
                                                 int* __restrict__ cursor,
                                                 unsigned short* __restrict__ slot,
                                                 const float* __restrict__ x,
                                                 unsigned short* __restrict__ x_bf,
                                                 const float* __restrict__ Wg,
                                                 const float* __restrict__ Wr,
                                                 unsigned short* __restrict__ wgf,
                                                 unsigned short* __restrict__ wrf,
                                                 int E, int ncvt) {
    int i = blockIdx.x * 256 + threadIdx.x;

    // --- slot: 4 edges/thread (atomics issued first, long latency) ---
    int base = i * 4;
    unsigned int s0, s1, s2, s3;
    bool full = (base + 4 <= E);
    if (full) {
        int4 c = *reinterpret_cast<const int4*>(col + base);
        s0 = (unsigned int)atomicAdd(&cursor[c.x], 1);
        s1 = (unsigned int)atomicAdd(&cursor[c.y], 1);
        s2 = (unsigned int)atomicAdd(&cursor[c.z], 1);
        s3 = (unsigned int)atomicAdd(&cursor[c.w], 1);
    } else {
        for (int e = base; e < E; ++e)
            slot[e] = (unsigned short)atomicAdd(&cursor[col[e]], 1);
    }

    // --- x -> bf16 (unscaled), 32 floats per thread ---
    if (i < ncvt) {
        const float4* xv = reinterpret_cast<const float4*>(x) + (size_t)i * 8;
        uint4* dst = reinterpret_cast<uint4*>(x_bf) + (size_t)i * 4;
#pragma unroll
        for (int j = 0; j < 4; ++j) {
            float4 a = xv[j * 2], b = xv[j * 2 + 1];
            uint4 o;
            o.x = f2bf(a.x) | (f2bf(a.y) << 16);
            o.y = f2bf(a.z) | (f2bf(a.w) << 16);
            o.z = f2bf(b.x) | (f2bf(b.y) << 16);
            o.w = f2bf(b.z) | (f2bf(b.w) << 16);
            dst[j] = o;
        }
    }

    // --- weight fragments (first 8192 threads) ---
    if (i < 8192) {
        int wsel = i >> 12;
        int u = i & 4095;
        int ct = u >> 8, kt = (u >> 6) & 3, l = u & 63;
        int k0 = kt * 32 + (l >> 4) * 8;
        int colw = ct * 16 + (l & 15);
        const float* W = wsel ? Wr : Wg;
        unsigned short* Wf = wsel ? wrf : wgf;
        uint4 o;
        unsigned int s[8];
#pragma unroll
        for (int e = 0; e < 8; ++e) s[e] = f2bf(W[(size_t)(k0 + e) * OUT_C + colw]);
        o.x = s[0] | (s[1] << 16); o.y = s[2] | (s[3] << 16);
        o.z = s[4] | (s[5] << 16); o.w = s[6] | (s[7] << 16);
        reinterpret_cast<uint4*>(Wf)[u] = o;
    }

    // --- pack + store slots (waits on atomic returns last) ---
    if (full) {
        uint4 o;
        o.x = (s0 & 0xffffu) | (s1 << 16);
        o.y = (s2 & 0xffffu) | (s3 << 16);
        *reinterpret_cast<uint2*>(slot + base) = make_uint2(o.x, o.y);
    }
}

// ---------- scan of deg (=cursor) -> per-block exclusive ptr + block sums + dinv ----------
__global__ __launch_bounds__(1024) void k_scan1(const int* __restrict__ deg, int* __restrict__ ptr,
                                                int* __restrict__ bsum, float* __restrict__ dinv, int n) {
    __shared__ int s[SCAN_BLK];
    int t = threadIdx.x;
    int i = blockIdx.x * SCAN_BLK + t;
    int v = (i < n) ? deg[i] : 0;
    s[t] = v;
    __syncthreads();
    for (int off = 1; off < SCAN_BLK; off <<= 1) {
        int add = (t >= off) ? s[t - off] : 0;
        __syncthreads();
        s[t] += add;
        __syncthreads();
    }
    if (i < n) { ptr[i] = s[t] - v; dinv[i] = rsqrtf((float)(v + 1)); }
    if (t == SCAN_BLK - 1) bsum[blockIdx.x] = s[t];
}

__global__ __launch_bounds__(64) void k_scan2(int* __restrict__ bsum, int nb) {
    __shared__ int s[64];
    int t = threadIdx.x;
    int v = (t < nb) ? bsum[t] : 0;
    s[t] = v;
    __syncthreads();
    for (int off = 1; off < 64; off <<= 1) {
        int add = (t >= off) ? s[t - off] : 0;
        __syncthreads();
        s[t] += add;
        __syncthreads();
    }
    if (t < nb) bsum[t] = s[t] - v;
}

// ---------- fused: atomic-free CSR placement + xs (dinv-scaled) convert ----------
__global__ __launch_bounds__(256) void k_placecvt(const int* __restrict__ row,
                                                  const int* __restrict__ col,
                                                  const int* __restrict__ ptr,
                                                  const int* __restrict__ bsum,
                                                  const unsigned short* __restrict__ slot,
                                                  int* __restrict__ csr_row,
                                                  const float* __restrict__ x,
                                                  const float* __restrict__ dinv,
                                                  unsigned short* __restrict__ xs_bf,
                                                  int E, int ncvt) {
    int i = blockIdx.x * 256 + threadIdx.x;

    // --- place: 4 edges/thread ---
    int base = i * 4;
    if (base + 4 <= E) {
        int4 r = *reinterpret_cast<const int4*>(row + base);
        int4 c = *reinterpret_cast<const int4*>(col + base);
        uint2 sp = *reinterpret_cast<const uint2*>(slot + base);
        csr_row[ptr[c.x] + bsum[c.x >> 10] + (sp.x & 0xffffu)] = r.x;
        csr_row[ptr[c.y] + bsum[c.y >> 10] + (sp.x >> 16)]     = r.y;
        csr_row[ptr[c.z] + bsum[c.z >> 10] + (sp.y & 0xffffu)] = r.z;
        csr_row[ptr[c.w] + bsum[c.w >> 10] + (sp.y >> 16)]     = r.w;
    } else {
        for (int e = base; e < E; ++e)
            csr_row[ptr[col[e]] + bsum[col[e] >> 10] + slot[e]] = row[e];
    }

    // --- xs = dinv * x -> bf16, 32 floats per thread (one quarter-row) ---
    if (i < ncvt) {
        float dn = dinv[i >> 2];
        const float4* xv = reinterpret_cast<const float4*>(x) + (size_t)i * 8;
        uint4* dst = reinterpret_cast<uint4*>(xs_bf) + (size_t)i * 4;
#pragma unroll
        for (int j = 0; j < 4; ++j) {
            float4 a = xv[j * 2], b = xv[j * 2 + 1];
            uint4 o;
            o.x = f2bf(a.x * dn) | (f2bf(a.y * dn) << 16);
            o.y = f2bf(a.z * dn) | (f2bf(a.w * dn) << 16);
            o.z = f2bf(b.x * dn) | (f2bf(b.y * dn) << 16);
            o.w = f2bf(b.z * dn) | (f2bf(b.w * dn) << 16);
            dst[j] = o;
        }
    }
}

// ---------- aggregation: agg[c] = dinv[c] * (xs[c] + sum_e xs[r]), unroll x8 ----------
__global__ __launch_bounds__(256) void k_agg(const unsigned int* __restrict__ xs32,
                                             const float* __restrict__ dinv,
                                             const int* __restrict__ ptr,
                                             const int* __restrict__ bsum,
                                             const int* __restrict__ csr_row,
                                             unsigned short* __restrict__ agg_bf, int n, int E) {
    int c = blockIdx.x * 4 + (threadIdx.x >> 6);
    if (c >= n) return;
    int lane = threadIdx.x & 63;
    float dc = dinv[c];
    unsigned int p = xs32[(size_t)c * 64 + lane];
    float a0 = bf_lo(p), a1 = bf_hi(p);
    int e   = ptr[c] + bsum[c >> 10];
    int end = (c + 1 < n) ? (ptr[c + 1] + bsum[(c + 1) >> 10]) : E;
    for (; e + 8 <= end; e += 8) {
        int r0 = csr_row[e],     r1 = csr_row[e + 1], r2 = csr_row[e + 2], r3 = csr_row[e + 3];
        int r4 = csr_row[e + 4], r5 = csr_row[e + 5], r6 = csr_row[e + 6], r7 = csr_row[e + 7];
        unsigned int q0 = xs32[(size_t)r0 * 64 + lane];
        unsigned int q1 = xs32[(size_t)r1 * 64 + lane];
        unsigned int q2 = xs32[(size_t)r2 * 64 + lane];
        unsigned int q3 = xs32[(size_t)r3 * 64 + lane];
        unsigned int q4 = xs32[(size_t)r4 * 64 + lane];
        unsigned int q5 = xs32[(size_t)r5 * 64 + lane];
        unsigned int q6 = xs32[(size_t)r6 * 64 + lane];
        unsigned int q7 = xs32[(size_t)r7 * 64 + lane];
        a0 += bf_lo(q0); a1 += bf_hi(q0);
        a0 += bf_lo(q1); a1 += bf_hi(q1);
        a0 += bf_lo(q2); a1 += bf_hi(q2);
        a0 += bf_lo(q3); a1 += bf_hi(q3);
        a0 += bf_lo(q4); a1 += bf_hi(q4);
        a0 += bf_lo(q5); a1 += bf_hi(q5);
        a0 += bf_lo(q6); a1 += bf_hi(q6);
        a0 += bf_lo(q7); a1 += bf_hi(q7);
    }
    for (; e < end; ++e) {
        unsigned int q = xs32[(size_t)csr_row[e] * 64 + lane];
        a0 += bf_lo(q); a1 += bf_hi(q);
    }
    a0 *= dc; a1 *= dc;
    *reinterpret_cast<unsigned int*>(agg_bf + (size_t)c * IN_C + lane * 2) = f2bf(a0) | (f2bf(a1) << 16);
}

// ---------- fused MFMA dual-GEMM (transposed output) + LN + ReLU + residual ----------
__global__ __launch_bounds__(512, 2) void k_mfma(const unsigned short* __restrict__ agg_bf,
                                                 const unsigned short* __restrict__ x_bf,
                                                 const unsigned short* __restrict__ wgf,
                                                 const unsigned short* __restrict__ wrf,
                                                 const float* __restrict__ bgc,
                                                 const float* __restrict__ gamma,
                                                 const float* __restrict__ beta,
                                                 const float* __restrict__ brc,
                                                 float* __restrict__ out, int n, int ntiles, int chunk) {
    int tid = threadIdx.x;
    int w = tid >> 6, l = tid & 63;
    int g = l >> 4, lc = l & 15;

    int t0 = blockIdx.x * chunk;
    int tend = t0 + chunk;
    if (tend > ntiles) tend = ntiles;
    if (t0 >= tend) return;

    bf16x8 Wgf[2][4], Wrf[2][4];
#pragma unroll
    for (int ct2 = 0; ct2 < 2; ++ct2)
#pragma unroll
        for (int kt = 0; kt < 4; ++kt) {
            size_t idx = ((size_t)((w * 2 + ct2) * 4 + kt) * 64 + l) * 8;
            Wgf[ct2][kt] = *reinterpret_cast<const bf16x8*>(wgf + idx);
            Wrf[ct2][kt] = *reinterpret_cast<const bf16x8*>(wrf + idx);
        }

    float4 Pbg[2], Pga[2], Pbe[2], Pbr[2];
#pragma unroll
    for (int ct2 = 0; ct2 < 2; ++ct2) {
        int c0 = (w * 2 + ct2) * 16 + g * 4;
        Pbg[ct2] = *reinterpret_cast<const float4*>(bgc + c0);
        Pga[ct2] = *reinterpret_cast<const float4*>(gamma + c0);
        Pbe[ct2] = *reinterpret_cast<const float4*>(beta + c0);
        Pbr[ct2] = *reinterpret_cast<const float4*>(brc + c0);
    }

    __shared__ float red1[2][8][16], red2[2][8][16];

    bf16x8 Fa[4], Fx[4];
    {
        int mrow = t0 * 16 + lc;
        if (mrow >= n) mrow = n - 1;
        const unsigned short* pa = agg_bf + (size_t)mrow * IN_C + g * 8;
        const unsigned short* px = x_bf   + (size_t)mrow * IN_C + g * 8;
#pragma unroll
        for (int kt = 0; kt < 4; ++kt) {
            Fa[kt] = *reinterpret_cast<const bf16x8*>(pa + kt * 32);
            Fx[kt] = *reinterpret_cast<const bf16x8*>(px + kt * 32);
        }
    }

    for (int t = t0; t < tend; ++t) {
        f32x4 Ag[2], Ar[2];
#pragma unroll
        for (int ct2 = 0; ct2 < 2; ++ct2) {
            Ag[ct2] = (f32x4){0.f, 0.f, 0.f, 0.f};
            Ar[ct2] = (f32x4){0.f, 0.f, 0.f, 0.f};
        }

#pragma unroll
        for (int kt = 0; kt < 4; ++kt)
#pragma unroll
            for (int ct2 = 0; ct2 < 2; ++ct2) {
                Ag[ct2] = __builtin_amdgcn_mfma_f32_16x16x32_bf16(Wgf[ct2][kt], Fa[kt], Ag[ct2], 0, 0, 0);
                Ar[ct2] = __builtin_amdgcn_mfma_f32_16x16x32_bf16(Wrf[ct2][kt], Fx[kt], Ar[ct2], 0, 0, 0);
            }

        {
            int tn = (t + 1 < tend) ? t + 1 : t;
            int mrow = tn * 16 + lc;
            if (mrow >= n) mrow = n - 1;
            const unsigned short* pa = agg_bf + (size_t)mrow * IN_C + g * 8;
            const unsigned short* px = x_bf   + (size_t)mrow * IN_C + g * 8;
#pragma unroll
            for (int kt = 0; kt < 4; ++kt) {
                Fa[kt] = *reinterpret_cast<const bf16x8*>(pa + kt * 32);
                Fx[kt] = *reinterpret_cast<const bf16x8*>(px + kt * 32);
            }
        }

        float s1 = 0.f, s2 = 0.f;
#pragma unroll
        for (int ct2 = 0; ct2 < 2; ++ct2) {
            const float* pb = reinterpret_cast<const float*>(&Pbg[ct2]);
#pragma unroll
            for (int r = 0; r < 4; ++r) {
                float v = Ag[ct2][r] + pb[r];
                Ag[ct2][r] = v;
                s1 += v; s2 += v * v;
            }
        }
        s1 += __shfl_xor(s1, 16); s2 += __shfl_xor(s2, 16);
        s1 += __shfl_xor(s1, 32); s2 += __shfl_xor(s2, 32);

        int buf = t & 1;
        if (l < 16) { red1[buf][w][lc] = s1; red2[buf][w][lc] = s2; }
        __syncthreads();

        float u1 = 0.f, u2 = 0.f;
#pragma unroll
        for (int wv = 0; wv < 8; ++wv) {
            u1 += red1[buf][wv][lc];
            u2 += red2[buf][wv][lc];
        }
        float mu  = u1 * (1.f / OUT_C);
        float var = u2 * (1.f / OUT_C) - mu * mu;
        float rs  = rsqrtf(var + LN_EPS);

        int rown = t * 16 + lc;
        if (rown < n) {
#pragma unroll
            for (int ct2 = 0; ct2 < 2; ++ct2) {
                const float* pg = reinterpret_cast<const float*>(&Pga[ct2]);
                const float* pe = reinterpret_cast<const float*>(&Pbe[ct2]);
                const float* pr = reinterpret_cast<const float*>(&Pbr[ct2]);
                f32x4 o;
#pragma unroll
                for (int r = 0; r < 4; ++r) {
                    float ln = (Ag[ct2][r] - mu) * rs * pg[r] + pe[r];
                    o[r] = fmaxf(ln, 0.f) + Ar[ct2][r] + pr[r];
                }
                *reinterpret_cast<f32x4*>(out + (size_t)rown * OUT_C + (w * 2 + ct2) * 16 + g * 4) = o;
            }
        }
    }
}

extern "C" void kernel_launch(void* const* d_in, const int* in_sizes, int n_in,
                              void* d_out, int out_size, void* d_ws, size_t ws_size,
                              hipStream_t stream) {
    const float* x     = (const float*)d_in[0];
    const int*   ei    = (const int*)d_in[1];
    const float* Wg    = (const float*)d_in[2];
    const float* bg    = (const float*)d_in[3];
    const float* gamma = (const float*)d_in[4];
    const float* beta  = (const float*)d_in[5];
    const float* Wr    = (const float*)d_in[6];
    const float* br    = (const float*)d_in[7];
    float* out = (float*)d_out;

    int N = in_sizes[0] / IN_C;
    int E = in_sizes[1] / 2;
    const int* row = ei;
    const int* col = ei + E;

    char* ws = (char*)d_ws;
    size_t off = 0;
    auto alloc = [&](size_t bytes) -> void* {
        void* p = ws + off;
        off += (bytes + 255) & ~(size_t)255;
        return p;
    };
    unsigned short* x_bf   = (unsigned short*)alloc((size_t)N * IN_C * 2);
    unsigned short* xs_bf  = (unsigned short*)alloc((size_t)N * IN_C * 2);
    unsigned short* agg_bf = (unsigned short*)alloc((size_t)N * IN_C * 2);
    unsigned short* wgf    = (unsigned short*)alloc((size_t)IN_C * OUT_C * 2);
    unsigned short* wrf    = (unsigned short*)alloc((size_t)IN_C * OUT_C * 2);
    float* dinv    = (float*)alloc((size_t)N * sizeof(float));
    int*   cursor  = (int*)alloc((size_t)N * sizeof(int));   // becomes deg
    int*   ptr     = (int*)alloc((size_t)(N + 1) * sizeof(int));
    int*   bsum    = (int*)alloc(64 * sizeof(int));
    unsigned short* slot = (unsigned short*)alloc((size_t)E * sizeof(unsigned short));
    int*   csr_row = (int*)alloc((size_t)E * sizeof(int));
    (void)ws_size; (void)n_in; (void)out_size;

    int nsb  = (N + SCAN_BLK - 1) / SCAN_BLK;           // 49
    int ncvt = N * (IN_C / 32);                          // 32 floats per thread -> 200000
    int nbig = ((E + 3) / 4 > ncvt ? (E + 3) / 4 : ncvt);
    int nbF  = (nbig + 255) / 256;                       // 782 blocks for fused kernels
    int ntiles = (N + 15) / 16;
    int ngrid  = 256;
    int chunk  = (ntiles + ngrid - 1) / ngrid;
    int n4     = (N + 3) / 4;

    k_zero    <<<(n4 + 255) / 256, 256, 0, stream>>>((int4*)cursor, n4);
    k_slotcvt <<<nbF, 256, 0, stream>>>(col, cursor, slot, x, x_bf, Wg, Wr, wgf, wrf, E, ncvt);
    k_scan1   <<<nsb, 1024, 0, stream>>>(cursor, ptr, bsum, dinv, N);
    k_scan2   <<<1, 64, 0, stream>>>(bsum, nsb);
    k_placecvt<<<nbF, 256, 0, stream>>>(row, col, ptr, bsum, slot, csr_row, x, dinv, xs_bf, E, ncvt);
    k_agg     <<<(N + 3) / 4, 256, 0, stream>>>((const unsigned int*)xs_bf, dinv, ptr, bsum, csr_row, agg_bf, N, E);
    k_mfma    <<<ngrid, 512, 0, stream>>>(agg_bf, x_bf, wgf, wrf, bg, gamma, beta, br, out, N, ntiles, chunk);
}